// Round 6
// baseline (392.397 us; speedup 1.0000x reference)
//
#include <hip/hip_runtime.h>
#include <hip/hip_bf16.h>

typedef __hip_bfloat16 bf16;
typedef __bf16 bfx8 __attribute__((ext_vector_type(8)));
typedef float f32x4 __attribute__((ext_vector_type(4)));

#define Bk   8
#define Ck   384
#define NHk  8
#define Dk   48
#define Dp   64
#define Nk   1024
#define O3   1152
#define NBLK 512

// ---------------------------------------------------------------------------
// R15: ONE kernel, PLAIN launch (512 blocks x 256, co-resident by
// construction: launch_bounds(256,2), 48KB LDS -> 2 blocks/CU x 256 CU).
// Manual grid barrier with agent-scope acq/rel atomics (compiler emits the
// cross-XCD cache ops: wbl2 on release, inv on acquire). Bounded spin ->
// cannot hang. R12's cooperative launch was likely rejected under graph
// capture (retcode unchecked -> nothing ran -> poison output).
//
// Phases: prep (grid-stride) -> qkv (576 units, n0=256) -> attn (R13
// verbatim; R14's PV-lag regressed and is dropped) -> proj (192 units,
// n0=256, no tail). Barrier counters at workspace tail, memset-zeroed.
// ---------------------------------------------------------------------------

__device__ __forceinline__ void gload_lds16(const bf16* src, void* dst)
{
    __builtin_amdgcn_global_load_lds(
        (const __attribute__((address_space(1))) void*)src,
        (__attribute__((address_space(3))) void*)dst, 16, 0, 0);
}

__device__ __forceinline__ int pack2(float a, float b)
{
    bf16 ha = __float2bfloat16(a), hb = __float2bfloat16(b);
    unsigned lo = *(unsigned short*)&ha, hi = *(unsigned short*)&hb;
    return (int)(lo | (hi << 16));
}

__device__ __forceinline__ ushort4 pack4(float v0, float v1, float v2, float v3)
{
    bf16 h0 = __float2bfloat16(v0), h1 = __float2bfloat16(v1);
    bf16 h2 = __float2bfloat16(v2), h3 = __float2bfloat16(v3);
    ushort4 pk;
    pk.x = *(unsigned short*)&h0; pk.y = *(unsigned short*)&h1;
    pk.z = *(unsigned short*)&h2; pk.w = *(unsigned short*)&h3;
    return pk;
}

__device__ __forceinline__ void grid_barrier(unsigned* cnt)
{
    __syncthreads();                      // all waves done + vmcnt drained
    if (threadIdx.x == 0) {
        __threadfence();
        __hip_atomic_fetch_add(cnt, 1u, __ATOMIC_ACQ_REL, __HIP_MEMORY_SCOPE_AGENT);
        unsigned g = 0;
        while (__hip_atomic_load(cnt, __ATOMIC_ACQUIRE, __HIP_MEMORY_SCOPE_AGENT)
                   < (unsigned)NBLK) {
            __builtin_amdgcn_s_sleep(8);
            if (++g > 2000000u) break;    // failsafe: wrong > hung
        }
        __threadfence();
    }
    __syncthreads();
}

__global__ __launch_bounds__(256, 2) void fused_kernel(
    const float* __restrict__ x,     const float* __restrict__ wqkv,
    const float* __restrict__ bqkv,  const float* __restrict__ wproj,
    const float* __restrict__ bproj, float* __restrict__ out,
    bf16* __restrict__ Xs, bf16* __restrict__ Wq, bf16* __restrict__ Wp,
    bf16* __restrict__ Qs, bf16* __restrict__ Ks, bf16* __restrict__ Vs,
    bf16* __restrict__ AO, unsigned* __restrict__ bars)
{
    __shared__ __align__(16) char sh_raw[49152];

    const int bid  = blockIdx.x;
    const int t    = threadIdx.x;
    const int wave = t >> 6;
    const int lane = t & 63;
    const int l15  = lane & 15, quad = lane >> 4;

    // ===== Phase 0: prep (grid-stride, no LDS) ============================
    for (int u = bid * 256 + t; u < 729088; u += 131072) {
        if (u < 393216) {
            int n = u & 1023, rest = u >> 10;
            int oct = rest % 48, b = rest / 48;
            const float* xb = x + (size_t)b * Ck * Nk;
            float f[8];
            #pragma unroll
            for (int e = 0; e < 8; ++e) f[e] = xb[(size_t)(oct * 8 + e) * Nk + n];
            int4 v = { pack2(f[0], f[1]), pack2(f[2], f[3]),
                       pack2(f[4], f[5]), pack2(f[6], f[7]) };
            bf16* dst = Xs + ((size_t)b * 64 + (n >> 4)) * 6144 + oct * 128 + (n & 15) * 8;
            *(int4*)dst = v;
        } else if (u < 448512) {
            int u1 = u - 393216;
            int o = u1 % 1152, oct = u1 / 1152;
            const float* src = wqkv + (size_t)o * Ck + oct * 8;
            int4 v = { pack2(src[0], src[1]), pack2(src[2], src[3]),
                       pack2(src[4], src[5]), pack2(src[6], src[7]) };
            bf16* dst = Wq + ((size_t)(o >> 4) * 48 + oct) * 128 + (o & 15) * 8;
            *(int4*)dst = v;
        } else if (u < 466944) {
            int u2 = u - 448512;
            int o = u2 % 384, oct = u2 / 384;
            const float* src = wproj + (size_t)o * Ck + oct * 8;
            int4 v = { pack2(src[0], src[1]), pack2(src[2], src[3]),
                       pack2(src[4], src[5]), pack2(src[6], src[7]) };
            bf16* dst = Wp + ((size_t)(o >> 4) * 48 + oct) * 128 + (o & 15) * 8;
            *(int4*)dst = v;
        } else {
            int i = u - 466944;      // 2 bufs x 64 heads x 64 grp x 2 chunks x 16
            int buf = i >> 17;
            int r17 = i & 131071;
            int head = r17 >> 11;
            int r11 = r17 & 2047;
            int g = r11 >> 5, c5 = r11 & 31;
            int cd = 6 + (c5 >> 4), e = c5 & 15;
            bf16* p = (buf ? Ks : Qs) + (size_t)head * 65536 +
                      ((size_t)g * 8 + cd) * 128 + e * 8;
            *(int4*)p = (int4){0, 0, 0, 0};
        }
    }

    grid_barrier(&bars[0]);

    // ===== Phase 1: QKV GEMM (576 units, n0=256; blocks 0-63 do 2) =======
    for (int u = bid; u < 576; u += NBLK) {
        const int bx = u & 3, v_ = u >> 2;
        const int by = v_ % 18, b = v_ / 18;
        const int o0 = by * 64, n0 = bx * 256;
        const int t3 = o0 / Ck;
        bf16* Wl = (bf16*)sh_raw;

        __syncthreads();               // prior unit's Wl reads done
        {
            const bf16* wsrc = Wq + (size_t)by * 24576;
            #pragma unroll
            for (int i = 0; i < 12; ++i) {
                int f = wave * 12 + i;
                gload_lds16(wsrc + f * 512 + lane * 8, sh_raw + f * 1024);
            }
        }
        const bf16* xg[4];
        #pragma unroll
        for (int i = 0; i < 4; ++i)
            xg[i] = Xs + ((size_t)(b * 64 + bx * 16 + wave * 4 + i) * 48) * 128 + lane * 8;
        const bf16* wl = Wl + lane * 8;

        f32x4 acc[16];
        #pragma unroll
        for (int i = 0; i < 16; ++i) acc[i] = (f32x4){0.f, 0.f, 0.f, 0.f};

        asm volatile("s_waitcnt vmcnt(0)" ::: "memory");
        __syncthreads();

        if (t3 < 2) {
            // D: row = o (quad*4+reg), col = n (l15) -> 8B ushort4 stores
            #pragma unroll
            for (int s = 0; s < 12; ++s) {
                bfx8 fx[4], fw[4];
                #pragma unroll
                for (int i = 0; i < 4; ++i) fx[i] = *(const bfx8*)(xg[i] + s * 512);
                #pragma unroll
                for (int j = 0; j < 4; ++j) fw[j] = *(const bfx8*)(wl + j * 6144 + s * 512);
                #pragma unroll
                for (int j = 0; j < 4; ++j)
                    #pragma unroll
                    for (int i = 0; i < 4; ++i)
                        acc[j * 4 + i] = __builtin_amdgcn_mfma_f32_16x16x32_bf16(
                            fw[j], fx[i], acc[j * 4 + i], 0, 0, 0);
            }
            const float qscale = 0.2082350964f;   // 48^-0.5 * log2(e)
            #pragma unroll
            for (int j = 0; j < 4; ++j) {
                int ob = o0 + j * 16 + quad * 4;
                float4 bi = *(const float4*)&bqkv[ob];
                int r  = ob - t3 * Ck;
                int hd = r / Dk, d0 = r - hd * Dk;
                bf16* hb = (t3 == 0 ? Qs : Ks) + (size_t)(b * NHk + hd) * 65536
                         + (d0 >> 3) * 128 + (d0 & 7);
                #pragma unroll
                for (int i = 0; i < 4; ++i) {
                    int npos = n0 + wave * 64 + i * 16 + l15;
                    f32x4 a = acc[j * 4 + i];
                    float v0 = a[0] + bi.x, v1 = a[1] + bi.y;
                    float v2 = a[2] + bi.z, v3 = a[3] + bi.w;
                    if (t3 == 0) { v0 *= qscale; v1 *= qscale; v2 *= qscale; v3 *= qscale; }
                    *(ushort4*)(hb + (size_t)(npos >> 4) * 1024 + (npos & 15) * 8) =
                        pack4(v0, v1, v2, v3);
                }
            }
        } else {
            // D: row = n (quad*4+reg), col = o (l15) -> 8B ushort4 stores
            #pragma unroll
            for (int s = 0; s < 12; ++s) {
                bfx8 fx[4], fw[4];
                #pragma unroll
                for (int i = 0; i < 4; ++i) fx[i] = *(const bfx8*)(xg[i] + s * 512);
                #pragma unroll
                for (int j = 0; j < 4; ++j) fw[j] = *(const bfx8*)(wl + j * 6144 + s * 512);
                #pragma unroll
                for (int i = 0; i < 4; ++i)
                    #pragma unroll
                    for (int j = 0; j < 4; ++j)
                        acc[i * 4 + j] = __builtin_amdgcn_mfma_f32_16x16x32_bf16(
                            fx[i], fw[j], acc[i * 4 + j], 0, 0, 0);
            }
            #pragma unroll
            for (int j = 0; j < 4; ++j) {
                int ov = o0 + j * 16 + l15;
                float bi = bqkv[ov];
                int r  = ov - 2 * Ck;
                int hd = r / Dk, d = r - hd * Dk;
                bf16* vbp = Vs + (size_t)(b * NHk + hd) * 49152
                          + (size_t)(d >> 4) * 16384 + (d & 15) * 8;
                #pragma unroll
                for (int i = 0; i < 4; ++i) {
                    int npb = n0 + wave * 64 + i * 16 + quad * 4;
                    f32x4 a = acc[i * 4 + j];
                    *(ushort4*)(vbp + (size_t)(npb >> 3) * 128 + (npb & 7)) =
                        pack4(a[0] + bi, a[1] + bi, a[2] + bi, a[3] + bi);
                }
            }
        }
    }

    grid_barrier(&bars[1]);

    // ===== Phase 2: attention (R13 verbatim; hd=bid&7 -> XCD pin) =========
    {
        bf16*  KbL  = (bf16*)sh_raw;                   // [2][4096]
        bf16*  VbL  = (bf16*)(sh_raw + 16384);         // [2][3072]
        short* Ps   = (short*)(sh_raw + 28672);        // [4][2][1152]
        float* sums = (float*)(sh_raw + 47104);        // [4][2][16]

        const int hd = bid & 7;
        const int b  = (bid >> 3) & 7;
        const int bx = bid >> 6;
        const int grp16 = (bx * 4 + wave) * 2;

        const bf16* qb = Qs + (size_t)(b * NHk + hd) * 65536;
        const bf16* kb = Ks + (size_t)(b * NHk + hd) * 65536;
        const bf16* vb = Vs + (size_t)(b * NHk + hd) * 49152;

        auto stage = [&](int buf, int k0) {
            const bf16* ksrc = kb + (size_t)k0 * 64;
            const bf16* vsrc = vb + (size_t)(k0 >> 3) * 128;
            char* kdst = (char*)(KbL + buf * 4096);
            char* vdst = (char*)(VbL + buf * 3072);
            #pragma unroll
            for (int i = 0; i < 4; ++i) {
                const int l = wave + i * 4;
                if (l < 14) {
                    const int piece = l >> 1, half = l & 1;
                    const bf16* src; char* dst;
                    if (piece < 4) {
                        src = ksrc + piece * 1024 + half * 512 + lane * 8;
                        dst = kdst + piece * 2048 + half * 1024;
                    } else {
                        const int dc = piece - 4;
                        src = vsrc + (size_t)dc * 16384 + half * 512 + lane * 8;
                        dst = vdst + dc * 2048 + half * 1024;
                    }
                    gload_lds16(src, dst);
                }
            }
        };

        stage(0, 0);

        bfx8 bq[2][2];
        #pragma unroll
        for (int qt = 0; qt < 2; ++qt) {
            const bf16* qp = qb + ((size_t)(grp16 + qt) * 8 + quad) * 128 + l15 * 8;
            bq[qt][0] = *(const bfx8*)(qp);
            bq[qt][1] = *(const bfx8*)(qp + 512);
        }

        float l_run[2] = {0.f, 0.f};
        f32x4 oacc[2][3];
        #pragma unroll
        for (int qt = 0; qt < 2; ++qt)
            #pragma unroll
            for (int dc = 0; dc < 3; ++dc) oacc[qt][dc] = (f32x4){0.f, 0.f, 0.f, 0.f};

        short* const PsW[2] = { Ps + wave * 2304, Ps + wave * 2304 + 1152 };
        const int lo = quad * 128 + l15 * 8;

        asm volatile("s_waitcnt vmcnt(0)" ::: "memory");
        __syncthreads();

        auto step = [&](int buf, int k0, bool pf) {
            if (pf) stage(buf ^ 1, k0 + 64);

            const bf16* Kc = KbL + buf * 4096;
            const bf16* Vc = VbL + buf * 3072;

            f32x4 sf[2][4];
            #pragma unroll
            for (int s = 0; s < 4; ++s) {
                const bfx8 kf0 = *(const bfx8*)(Kc + s * 1024 + lo);
                const bfx8 kf1 = *(const bfx8*)(Kc + s * 1024 + 512 + lo);
                #pragma unroll
                for (int qt = 0; qt < 2; ++qt) {
                    f32x4 z = (f32x4){0.f, 0.f, 0.f, 0.f};
                    z = __builtin_amdgcn_mfma_f32_16x16x32_bf16(kf0, bq[qt][0], z, 0, 0, 0);
                    z = __builtin_amdgcn_mfma_f32_16x16x32_bf16(kf1, bq[qt][1], z, 0, 0, 0);
                    sf[qt][s] = z;
                }
            }

            #pragma unroll
            for (int qt = 0; qt < 2; ++qt) {
                float lsum = 0.f;
                #pragma unroll
                for (int s = 0; s < 4; ++s) {
                    float e0 = __builtin_amdgcn_exp2f(sf[qt][s][0]);
                    float e1 = __builtin_amdgcn_exp2f(sf[qt][s][1]);
                    float e2 = __builtin_amdgcn_exp2f(sf[qt][s][2]);
                    float e3 = __builtin_amdgcn_exp2f(sf[qt][s][3]);
                    lsum += (e0 + e1) + (e2 + e3);
                    *(ushort4*)&PsW[qt][l15 * 72 + s * 16 + quad * 4] =
                        pack4(e0, e1, e2, e3);
                }
                l_run[qt] += lsum;
            }

            #pragma unroll
            for (int qt = 0; qt < 2; ++qt) {
                const bfx8 ap0 = *(const bfx8*)&PsW[qt][l15 * 72 + quad * 8];
                const bfx8 ap1 = *(const bfx8*)&PsW[qt][l15 * 72 + 32 + quad * 8];
                #pragma unroll
                for (int dc = 0; dc < 3; ++dc) {
                    const bfx8 bv0 = *(const bfx8*)(Vc + dc * 1024 + lo);
                    const bfx8 bv1 = *(const bfx8*)(Vc + dc * 1024 + 512 + lo);
                    oacc[qt][dc] = __builtin_amdgcn_mfma_f32_16x16x32_bf16(
                        ap0, bv0, oacc[qt][dc], 0, 0, 0);
                    oacc[qt][dc] = __builtin_amdgcn_mfma_f32_16x16x32_bf16(
                        ap1, bv1, oacc[qt][dc], 0, 0, 0);
                }
            }

            asm volatile("s_waitcnt vmcnt(0)" ::: "memory");
            __syncthreads();
        };

        #pragma unroll 1
        for (int k0 = 0; k0 < Nk; k0 += 128) {
            step(0, k0, true);
            step(1, k0 + 64, k0 + 128 < Nk);
        }

        #pragma unroll
        for (int qt = 0; qt < 2; ++qt) {
            float lt = l_run[qt];
            lt += __shfl_xor(lt, 16, 64);
            lt += __shfl_xor(lt, 32, 64);
            sums[(wave * 2 + qt) * 16 + l15] = lt;
        }
        asm volatile("s_waitcnt lgkmcnt(0)" ::: "memory");

        #pragma unroll
        for (int qt = 0; qt < 2; ++qt) {
            short* OsW = PsW[qt];
            #pragma unroll
            for (int r = 0; r < 4; ++r) {
                int qi = quad * 4 + r;
                float rli = 1.0f / sums[(wave * 2 + qt) * 16 + qi];
                #pragma unroll
                for (int dcc = 0; dcc < 3; ++dcc) {
                    bf16 hb = __float2bfloat16(oacc[qt][dcc][r] * rli);
                    OsW[qi * 64 + dcc * 16 + l15] = *(short*)&hb;
                }
            }
        }
        asm volatile("s_waitcnt lgkmcnt(0)" ::: "memory");

        #pragma unroll
        for (int qt = 0; qt < 2; ++qt) {
            bf16* aob = AO + (((size_t)b * 64 + grp16 + qt) * 48 + hd * 6) * 128;
            short* OsW = PsW[qt];
            int u = lane;
            int4 v = *(const int4*)&OsW[(u & 15) * 64 + (u >> 4) * 8];
            *(int4*)(aob + u * 8) = v;
            if (lane < 32) {
                int u2 = 64 + lane;
                int4 v2 = *(const int4*)&OsW[(u2 & 15) * 64 + (u2 >> 4) * 8];
                *(int4*)(aob + u2 * 8) = v2;
            }
        }
    }

    grid_barrier(&bars[2]);

    // ===== Phase 3: projection GEMM (192 units, n0=256, no tail) ==========
    if (bid < 192) {
        const int b = bid / 24, r_ = bid % 24;
        const int by = r_ >> 2, bx = r_ & 3;
        const int o0 = by * 64, n0 = bx * 256;
        bf16* Wl = (bf16*)sh_raw;

        {
            const bf16* wsrc = Wp + (size_t)by * 24576;
            #pragma unroll
            for (int i = 0; i < 12; ++i) {
                int f = wave * 12 + i;
                gload_lds16(wsrc + f * 512 + lane * 8, sh_raw + f * 1024);
            }
        }
        const bf16* ag[4];
        #pragma unroll
        for (int i = 0; i < 4; ++i)
            ag[i] = AO + ((size_t)(b * 64 + bx * 16 + wave * 4 + i) * 48) * 128 + lane * 8;
        const bf16* wl = Wl + lane * 8;

        f32x4 acc[16];
        #pragma unroll
        for (int i = 0; i < 16; ++i) acc[i] = (f32x4){0.f, 0.f, 0.f, 0.f};

        asm volatile("s_waitcnt vmcnt(0)" ::: "memory");
        __syncthreads();

        // D: row = n (quad*4+reg), col = o (l15) -> float4 stores
        #pragma unroll
        for (int s = 0; s < 12; ++s) {
            bfx8 fx[4], fw[4];
            #pragma unroll
            for (int i = 0; i < 4; ++i) fx[i] = *(const bfx8*)(ag[i] + s * 512);
            #pragma unroll
            for (int j = 0; j < 4; ++j) fw[j] = *(const bfx8*)(wl + j * 6144 + s * 512);
            #pragma unroll
            for (int i = 0; i < 4; ++i)
                #pragma unroll
                for (int j = 0; j < 4; ++j)
                    acc[i * 4 + j] = __builtin_amdgcn_mfma_f32_16x16x32_bf16(
                        fx[i], fw[j], acc[i * 4 + j], 0, 0, 0);
        }

        #pragma unroll
        for (int j = 0; j < 4; ++j) {
            int o = o0 + j * 16 + l15;
            float bi = bproj[o];
            #pragma unroll
            for (int i = 0; i < 4; ++i) {
                int npb = n0 + wave * 64 + i * 16 + quad * 4;
                f32x4 a = acc[i * 4 + j];
                float4 v = { a[0] + bi, a[1] + bi, a[2] + bi, a[3] + bi };
                *(float4*)&out[((size_t)b * Ck + o) * Nk + npb] = v;
            }
        }
    }
}

extern "C" void kernel_launch(void* const* d_in, const int* in_sizes, int n_in,
                              void* d_out, int out_size, void* d_ws, size_t ws_size,
                              hipStream_t stream)
{
    const float* x      = (const float*)d_in[0];
    const float* w_qkv  = (const float*)d_in[1];
    const float* b_qkv  = (const float*)d_in[2];
    const float* w_proj = (const float*)d_in[3];
    const float* b_proj = (const float*)d_in[4];
    float* out = (float*)d_out;

    const size_t XT_SEG = (size_t)Bk * Nk * Ck;          // 3,145,728
    const size_t WQ_SEG = (size_t)O3 * Ck;               //   442,368
    const size_t WP_SEG = (size_t)Ck * Ck;               //   147,456
    const size_t QK_SEG = (size_t)Bk * NHk * Nk * Dp;    // 4,194,304
    const size_t V_SEG  = (size_t)Bk * NHk * Dk * Nk;    // 3,145,728
    const size_t AO_SEG = (size_t)Bk * Nk * Ck;          // 3,145,728

    bf16* Xs = (bf16*)d_ws;
    bf16* Wq = Xs + XT_SEG;
    bf16* Wp = Wq + WQ_SEG;
    bf16* Qs = Wp + WP_SEG;
    bf16* Ks = Qs + QK_SEG;
    bf16* Vs = Ks + QK_SEG;
    bf16* AO = Vs + V_SEG;
    unsigned* bars = (unsigned*)(AO + AO_SEG);           // byte off 36,831,232

    hipMemsetAsync(bars, 0, 64, stream);
    fused_kernel<<<NBLK, 256, 0, stream>>>(
        x, w_qkv, b_qkv, w_proj, b_proj, out,
        Xs, Wq, Wp, Qs, Ks, Vs, AO, bars);
}

// Round 7
// 124.132 us; speedup vs baseline: 3.1611x; 3.1611x over previous
//
#include <hip/hip_runtime.h>
#include <hip/hip_bf16.h>

typedef __hip_bfloat16 bf16;
typedef __bf16 bfx8 __attribute__((ext_vector_type(8)));
typedef float f32x4 __attribute__((ext_vector_type(4)));

#define Bk   8
#define Ck   384
#define NHk  8
#define Dk   48
#define Dp   64
#define Nk   1024
#define O3   1152

// ---------------------------------------------------------------------------
// R16 = R13 (verified 120.1us) with:
//   - qkv: R15-phase-1 structure (n0=256, 576 blocks, verified correct in the
//     passing R15 run), grid (b,by,bx) so id%8==b pins X-slab+W per XCD L2.
//   - proj: R15-phase-3 (n0=256, 192 blocks, single round), same pinning.
//   - attn: 3-buffer counted-vmcnt pipeline (T4): stage chunk c+2 at end of
//     iter c; top-of-iter waits vmcnt(4|3) for the CONSUMED chunk only, raw
//     s_barrier + sched_barrier(0); setprio(1) around MFMA clusters (T5).
//     4 loads stay in flight across every barrier (was full vmcnt(0) drain).
// Fusion abandoned: R15 measured manual grid barriers at ~80us each
// (MfmaUtil 2.9% over 335us); kernel boundaries are cheaper.
// Known harness floor: 42us workspace-poison fill is serialized in the
// timed window; R13's 120 = 42 fill + ~78 kernels+gaps.
// ---------------------------------------------------------------------------

__device__ __forceinline__ void gload_lds16(const bf16* src, void* dst)
{
    __builtin_amdgcn_global_load_lds(
        (const __attribute__((address_space(1))) void*)src,
        (__attribute__((address_space(3))) void*)dst, 16, 0, 0);
}

__device__ __forceinline__ int pack2(float a, float b)
{
    bf16 ha = __float2bfloat16(a), hb = __float2bfloat16(b);
    unsigned lo = *(unsigned short*)&ha, hi = *(unsigned short*)&hb;
    return (int)(lo | (hi << 16));
}

__device__ __forceinline__ ushort4 pack4(float v0, float v1, float v2, float v3)
{
    bf16 h0 = __float2bfloat16(v0), h1 = __float2bfloat16(v1);
    bf16 h2 = __float2bfloat16(v2), h3 = __float2bfloat16(v3);
    ushort4 pk;
    pk.x = *(unsigned short*)&h0; pk.y = *(unsigned short*)&h1;
    pk.z = *(unsigned short*)&h2; pk.w = *(unsigned short*)&h3;
    return pk;
}

// ---------------------------------------------------------------------------
// Prep: one unit per thread (verbatim R13, verified).
// ---------------------------------------------------------------------------
__global__ __launch_bounds__(256) void prep_kernel(
    const float* __restrict__ x, bf16* __restrict__ Xs,
    const float* __restrict__ wq, const float* __restrict__ wp,
    bf16* __restrict__ Wq, bf16* __restrict__ Wp,
    bf16* __restrict__ Qs, bf16* __restrict__ Ks)
{
    const int u = blockIdx.x * 256 + threadIdx.x;
    if (u < 393216) {
        int n = u & 1023, rest = u >> 10;
        int oct = rest % 48, b = rest / 48;
        const float* xb = x + (size_t)b * Ck * Nk;
        float f[8];
        #pragma unroll
        for (int e = 0; e < 8; ++e) f[e] = xb[(size_t)(oct * 8 + e) * Nk + n];
        int4 v = { pack2(f[0], f[1]), pack2(f[2], f[3]),
                   pack2(f[4], f[5]), pack2(f[6], f[7]) };
        bf16* dst = Xs + ((size_t)b * 64 + (n >> 4)) * 6144 + oct * 128 + (n & 15) * 8;
        *(int4*)dst = v;
    } else if (u < 448512) {
        int u1 = u - 393216;
        int o = u1 % 1152, oct = u1 / 1152;
        const float* src = wq + (size_t)o * Ck + oct * 8;
        int4 v = { pack2(src[0], src[1]), pack2(src[2], src[3]),
                   pack2(src[4], src[5]), pack2(src[6], src[7]) };
        bf16* dst = Wq + ((size_t)(o >> 4) * 48 + oct) * 128 + (o & 15) * 8;
        *(int4*)dst = v;
    } else if (u < 466944) {
        int u2 = u - 448512;
        int o = u2 % 384, oct = u2 / 384;
        const float* src = wp + (size_t)o * Ck + oct * 8;
        int4 v = { pack2(src[0], src[1]), pack2(src[2], src[3]),
                   pack2(src[4], src[5]), pack2(src[6], src[7]) };
        bf16* dst = Wp + ((size_t)(o >> 4) * 48 + oct) * 128 + (o & 15) * 8;
        *(int4*)dst = v;
    } else {
        int i = u - 466944;      // 2 bufs x 64 heads x 64 grp x 2 chunks x 16
        int buf = i >> 17;
        int r17 = i & 131071;
        int head = r17 >> 11;
        int r11 = r17 & 2047;
        int g = r11 >> 5, c5 = r11 & 31;
        int cd = 6 + (c5 >> 4), e = c5 & 15;
        bf16* p = (buf ? Ks : Qs) + (size_t)head * 65536 +
                  ((size_t)g * 8 + cd) * 128 + e * 8;
        *(int4*)p = (int4){0, 0, 0, 0};
    }
}

// ---------------------------------------------------------------------------
// Kernel 1: QKV GEMM, n0=256 (R15-phase-1, verified). Grid (b=8, by=18,
// bx=4): linear id % 8 == b -> per-XCD working set = X slabs of one batch
// (768 KB) + W (2.25 MB) < 4 MB L2.
// ---------------------------------------------------------------------------
__global__ __launch_bounds__(256, 2) void qkv_mfma_kernel(
    const bf16* __restrict__ Xs, const bf16* __restrict__ Wq,
    const float* __restrict__ bias,
    bf16* __restrict__ Qs, bf16* __restrict__ Ks, bf16* __restrict__ Vs)
{
    __shared__ __align__(16) bf16 Wl[24576];    // 48 KB

    const int b    = blockIdx.x;
    const int by   = blockIdx.y;
    const int bx   = blockIdx.z;
    const int o0   = by * 64;
    const int n0   = bx * 256;
    const int wave = threadIdx.x >> 6;
    const int lane = threadIdx.x & 63;
    const int l15  = lane & 15, quad = lane >> 4;
    const int t3   = o0 / Ck;

    {
        const bf16* wsrc = Wq + (size_t)by * 24576;
        #pragma unroll
        for (int i = 0; i < 12; ++i) {
            int f = wave * 12 + i;
            gload_lds16(wsrc + f * 512 + lane * 8, (char*)Wl + f * 1024);
        }
    }

    const bf16* xg[4];
    #pragma unroll
    for (int i = 0; i < 4; ++i)
        xg[i] = Xs + ((size_t)(b * 64 + bx * 16 + wave * 4 + i) * 48) * 128 + lane * 8;
    const bf16* wl = Wl + lane * 8;

    bfx8 fx0[4];
    #pragma unroll
    for (int i = 0; i < 4; ++i) fx0[i] = *(const bfx8*)(xg[i]);

    f32x4 acc[16];
    #pragma unroll
    for (int i = 0; i < 16; ++i) acc[i] = (f32x4){0.f, 0.f, 0.f, 0.f};

    asm volatile("s_waitcnt vmcnt(0)" ::: "memory");
    __syncthreads();

    if (t3 < 2) {
        // D: row = o (quad*4+reg), col = n (l15) -> 8B ushort4 stores
        #pragma unroll
        for (int s = 0; s < 12; ++s) {
            bfx8 fx[4], fw[4];
            #pragma unroll
            for (int i = 0; i < 4; ++i)
                fx[i] = (s == 0) ? fx0[i] : *(const bfx8*)(xg[i] + s * 512);
            #pragma unroll
            for (int j = 0; j < 4; ++j) fw[j] = *(const bfx8*)(wl + j * 6144 + s * 512);
            #pragma unroll
            for (int j = 0; j < 4; ++j)
                #pragma unroll
                for (int i = 0; i < 4; ++i)
                    acc[j * 4 + i] = __builtin_amdgcn_mfma_f32_16x16x32_bf16(
                        fw[j], fx[i], acc[j * 4 + i], 0, 0, 0);
        }
        const float qscale = 0.2082350964f;   // 48^-0.5 * log2(e)
        #pragma unroll
        for (int j = 0; j < 4; ++j) {
            int ob = o0 + j * 16 + quad * 4;
            float4 bi = *(const float4*)&bias[ob];
            int r  = ob - t3 * Ck;
            int hd = r / Dk, d0 = r - hd * Dk;
            bf16* hb = (t3 == 0 ? Qs : Ks) + (size_t)(b * NHk + hd) * 65536
                     + (d0 >> 3) * 128 + (d0 & 7);
            #pragma unroll
            for (int i = 0; i < 4; ++i) {
                int npos = n0 + wave * 64 + i * 16 + l15;
                f32x4 a = acc[j * 4 + i];
                float v0 = a[0] + bi.x, v1 = a[1] + bi.y;
                float v2 = a[2] + bi.z, v3 = a[3] + bi.w;
                if (t3 == 0) { v0 *= qscale; v1 *= qscale; v2 *= qscale; v3 *= qscale; }
                *(ushort4*)(hb + (size_t)(npos >> 4) * 1024 + (npos & 15) * 8) =
                    pack4(v0, v1, v2, v3);
            }
        }
    } else {
        // D: row = n (quad*4+reg), col = o (l15) -> 8B ushort4 stores
        #pragma unroll
        for (int s = 0; s < 12; ++s) {
            bfx8 fx[4], fw[4];
            #pragma unroll
            for (int i = 0; i < 4; ++i)
                fx[i] = (s == 0) ? fx0[i] : *(const bfx8*)(xg[i] + s * 512);
            #pragma unroll
            for (int j = 0; j < 4; ++j) fw[j] = *(const bfx8*)(wl + j * 6144 + s * 512);
            #pragma unroll
            for (int i = 0; i < 4; ++i)
                #pragma unroll
                for (int j = 0; j < 4; ++j)
                    acc[i * 4 + j] = __builtin_amdgcn_mfma_f32_16x16x32_bf16(
                        fx[i], fw[j], acc[i * 4 + j], 0, 0, 0);
        }
        #pragma unroll
        for (int j = 0; j < 4; ++j) {
            int ov = o0 + j * 16 + l15;
            float bi = bias[ov];
            int r  = ov - 2 * Ck;
            int hd = r / Dk, d = r - hd * Dk;
            bf16* vbp = Vs + (size_t)(b * NHk + hd) * 49152
                      + (size_t)(d >> 4) * 16384 + (d & 15) * 8;
            #pragma unroll
            for (int i = 0; i < 4; ++i) {
                int npb = n0 + wave * 64 + i * 16 + quad * 4;
                f32x4 a = acc[i * 4 + j];
                *(ushort4*)(vbp + (size_t)(npb >> 3) * 128 + (npb & 7)) =
                    pack4(a[0] + bi, a[1] + bi, a[2] + bi, a[3] + bi);
            }
        }
    }
}

// ---------------------------------------------------------------------------
// Kernel 2 (R16): attention with 3-buffer counted-vmcnt pipeline.
//   prologue: stage(0), stage(1).
//   iter c: wait vmcnt(4|3) [chunk c's loads done; c+1's stay in flight] ->
//   raw s_barrier -> QK(c) -> exp2 -> PV(c) -> stage(c+2).
//   stage(c+2) writes slot (c+2)%3 = (c-1)%3, whose readers all passed the
//   iter-c barrier. LDS: 24K K + 18K V + 18K P + 0.5K = 62KB -> 2 blk/CU.
// ---------------------------------------------------------------------------
__global__ __launch_bounds__(256, 2) void attn_kernel(
    const bf16* __restrict__ Qs, const bf16* __restrict__ Ks,
    const bf16* __restrict__ Vs, bf16* __restrict__ AO)
{
    __shared__ __align__(16) bf16 KbL[3][4096];   // 8 KB per slot
    __shared__ __align__(16) bf16 VbL[3][3072];   // 6 KB per slot
    __shared__ __align__(16) short Ps[4 * 2304];  // per-wave P (2 qt)
    __shared__ float sums[4][2][16];

    const int hd   = blockIdx.x;
    const int b    = blockIdx.y;
    const int bx   = blockIdx.z;       // 8 q-slabs of 128
    const int t    = threadIdx.x;
    const int wave = t >> 6;
    const int lane = t & 63;
    const int l15  = lane & 15;
    const int quad = lane >> 4;
    const int grp16 = (bx * 4 + wave) * 2;   // first 16-q group of this wave

    const bf16* qb = Qs + (size_t)(b * NHk + hd) * 65536;
    const bf16* kb = Ks + (size_t)(b * NHk + hd) * 65536;
    const bf16* vb = Vs + (size_t)(b * NHk + hd) * 49152;

    // 14 x 1KB pieces/chunk over 4 waves: waves 0,1 issue 4; waves 2,3 issue 3.
    auto stage = [&](int slot, int k0) {
        const bf16* ksrc = kb + (size_t)k0 * 64;
        const bf16* vsrc = vb + (size_t)(k0 >> 3) * 128;
        char* kdst = (char*)&KbL[slot][0];
        char* vdst = (char*)&VbL[slot][0];
        #pragma unroll
        for (int i = 0; i < 4; ++i) {
            const int l = wave + i * 4;
            if (l < 14) {
                const int piece = l >> 1, half = l & 1;
                const bf16* src; char* dst;
                if (piece < 4) {
                    src = ksrc + piece * 1024 + half * 512 + lane * 8;
                    dst = kdst + piece * 2048 + half * 1024;
                } else {
                    const int dc = piece - 4;
                    src = vsrc + (size_t)dc * 16384 + half * 512 + lane * 8;
                    dst = vdst + dc * 2048 + half * 1024;
                }
                gload_lds16(src, dst);
            }
        }
    };

    stage(0, 0);
    stage(1, 64);

    // Q fragments (burst loads): B[k=d][n=q=l15] for 2 q-tiles
    bfx8 bq[2][2];
    #pragma unroll
    for (int qt = 0; qt < 2; ++qt) {
        const bf16* qp = qb + ((size_t)(grp16 + qt) * 8 + quad) * 128 + l15 * 8;
        bq[qt][0] = *(const bfx8*)(qp);
        bq[qt][1] = *(const bfx8*)(qp + 512);
    }

    float l_run[2] = {0.f, 0.f};
    f32x4 oacc[2][3];
    #pragma unroll
    for (int qt = 0; qt < 2; ++qt)
        #pragma unroll
        for (int dc = 0; dc < 3; ++dc) oacc[qt][dc] = (f32x4){0.f, 0.f, 0.f, 0.f};

    short* const PsW[2] = { Ps + wave * 2304, Ps + wave * 2304 + 1152 };
    const int lo = quad * 128 + l15 * 8;     // elem offset inside a 2KB piece

    #pragma unroll 1
    for (int c = 0; c < 16; ++c) {
        // wait: chunk c's pieces landed (c+1's 4|3 loads stay in flight)
        if (c < 15) {
            if (wave < 2) asm volatile("s_waitcnt vmcnt(4)" ::: "memory");
            else          asm volatile("s_waitcnt vmcnt(3)" ::: "memory");
        } else {
            asm volatile("s_waitcnt vmcnt(0)" ::: "memory");
        }
        __builtin_amdgcn_sched_barrier(0);
        __builtin_amdgcn_s_barrier();
        __builtin_amdgcn_sched_barrier(0);

        const int slot = c % 3;
        const bf16* Kc = &KbL[slot][0];
        const bf16* Vc = &VbL[slot][0];

        // QK(c): S^T = K Q^T, D[key][q]
        f32x4 sf[2][4];
        __builtin_amdgcn_s_setprio(1);
        #pragma unroll
        for (int s = 0; s < 4; ++s) {
            const bfx8 kf0 = *(const bfx8*)(Kc + s * 1024 + lo);
            const bfx8 kf1 = *(const bfx8*)(Kc + s * 1024 + 512 + lo);
            #pragma unroll
            for (int qt = 0; qt < 2; ++qt) {
                f32x4 z = (f32x4){0.f, 0.f, 0.f, 0.f};
                z = __builtin_amdgcn_mfma_f32_16x16x32_bf16(kf0, bq[qt][0], z, 0, 0, 0);
                z = __builtin_amdgcn_mfma_f32_16x16x32_bf16(kf1, bq[qt][1], z, 0, 0, 0);
                sf[qt][s] = z;
            }
        }
        __builtin_amdgcn_s_setprio(0);

        // exp2(c) -> P, accumulate l
        #pragma unroll
        for (int qt = 0; qt < 2; ++qt) {
            float lsum = 0.f;
            #pragma unroll
            for (int s = 0; s < 4; ++s) {
                float e0 = __builtin_amdgcn_exp2f(sf[qt][s][0]);
                float e1 = __builtin_amdgcn_exp2f(sf[qt][s][1]);
                float e2 = __builtin_amdgcn_exp2f(sf[qt][s][2]);
                float e3 = __builtin_amdgcn_exp2f(sf[qt][s][3]);
                lsum += (e0 + e1) + (e2 + e3);
                *(ushort4*)&PsW[qt][l15 * 72 + s * 16 + quad * 4] =
                    pack4(e0, e1, e2, e3);
            }
            l_run[qt] += lsum;
        }

        // PV(c)
        __builtin_amdgcn_s_setprio(1);
        #pragma unroll
        for (int qt = 0; qt < 2; ++qt) {
            const bfx8 ap0 = *(const bfx8*)&PsW[qt][l15 * 72 + quad * 8];
            const bfx8 ap1 = *(const bfx8*)&PsW[qt][l15 * 72 + 32 + quad * 8];
            #pragma unroll
            for (int dc = 0; dc < 3; ++dc) {
                const bfx8 bv0 = *(const bfx8*)(Vc + dc * 1024 + lo);
                const bfx8 bv1 = *(const bfx8*)(Vc + dc * 1024 + 512 + lo);
                oacc[qt][dc] = __builtin_amdgcn_mfma_f32_16x16x32_bf16(
                    ap0, bv0, oacc[qt][dc], 0, 0, 0);
                oacc[qt][dc] = __builtin_amdgcn_mfma_f32_16x16x32_bf16(
                    ap1, bv1, oacc[qt][dc], 0, 0, 0);
            }
        }
        __builtin_amdgcn_s_setprio(0);

        // prefetch chunk c+2 into slot (c+2)%3 = (c-1)%3: its readers all
        // passed this iteration's barrier already.
        if (c + 2 < 16) stage((c + 2) % 3, (c + 2) * 64);
    }

    // l reduction over quads
    #pragma unroll
    for (int qt = 0; qt < 2; ++qt) {
        float lt = l_run[qt];
        lt += __shfl_xor(lt, 16, 64);
        lt += __shfl_xor(lt, 32, 64);
        sums[wave][qt][l15] = lt;
    }
    asm volatile("s_waitcnt lgkmcnt(0)" ::: "memory");

    // normalize into per-wave LDS (reuse P region), then swizzled AO store
    #pragma unroll
    for (int qt = 0; qt < 2; ++qt) {
        short* OsW = PsW[qt];   // 16*64 = 1024 shorts < 1152 region
        #pragma unroll
        for (int r = 0; r < 4; ++r) {
            int qi = quad * 4 + r;
            float rli = 1.0f / sums[wave][qt][qi];
            #pragma unroll
            for (int dcc = 0; dcc < 3; ++dcc) {
                bf16 hb = __float2bfloat16(oacc[qt][dcc][r] * rli);
                OsW[qi * 64 + dcc * 16 + l15] = *(short*)&hb;
            }
        }
    }
    asm volatile("s_waitcnt lgkmcnt(0)" ::: "memory");

    #pragma unroll
    for (int qt = 0; qt < 2; ++qt) {
        bf16* aob = AO + (((size_t)b * 64 + grp16 + qt) * 48 + hd * 6) * 128;
        short* OsW = PsW[qt];
        int u = lane;
        int4 v = *(const int4*)&OsW[(u & 15) * 64 + (u >> 4) * 8];
        *(int4*)(aob + u * 8) = v;
        if (lane < 32) {
            int u2 = 64 + lane;
            int4 v2 = *(const int4*)&OsW[(u2 & 15) * 64 + (u2 >> 4) * 8];
            *(int4*)(aob + u2 * 8) = v2;
        }
    }
}

// ---------------------------------------------------------------------------
// Kernel 3: projection GEMM, n0=256 (R15-phase-3, verified), 192 blocks,
// single occupancy round. Grid (b=8, by=6, bx=4): id%8==b -> XCD pinning.
// ---------------------------------------------------------------------------
__global__ __launch_bounds__(256, 2) void proj_mfma_kernel(
    const bf16* __restrict__ AO, const bf16* __restrict__ Wp,
    const float* __restrict__ bias, float* __restrict__ out)
{
    __shared__ __align__(16) bf16 Wl[24576];    // 48 KB

    const int b    = blockIdx.x;
    const int by   = blockIdx.y;
    const int bx   = blockIdx.z;
    const int o0   = by * 64;
    const int n0   = bx * 256;
    const int wave = threadIdx.x >> 6;
    const int lane = threadIdx.x & 63;
    const int l15  = lane & 15, quad = lane >> 4;

    {
        const bf16* wsrc = Wp + (size_t)by * 24576;
        #pragma unroll
        for (int i = 0; i < 12; ++i) {
            int f = wave * 12 + i;
            gload_lds16(wsrc + f * 512 + lane * 8, (char*)Wl + f * 1024);
        }
    }

    const bf16* ag[4];
    #pragma unroll
    for (int i = 0; i < 4; ++i)
        ag[i] = AO + ((size_t)(b * 64 + bx * 16 + wave * 4 + i) * 48) * 128 + lane * 8;
    const bf16* wl = Wl + lane * 8;

    bfx8 fx0[4];
    #pragma unroll
    for (int i = 0; i < 4; ++i) fx0[i] = *(const bfx8*)(ag[i]);

    f32x4 acc[16];
    #pragma unroll
    for (int i = 0; i < 16; ++i) acc[i] = (f32x4){0.f, 0.f, 0.f, 0.f};

    asm volatile("s_waitcnt vmcnt(0)" ::: "memory");
    __syncthreads();

    // D: row = n (quad*4+reg), col = o (l15) -> float4 stores
    #pragma unroll
    for (int s = 0; s < 12; ++s) {
        bfx8 fx[4], fw[4];
        #pragma unroll
        for (int i = 0; i < 4; ++i)
            fx[i] = (s == 0) ? fx0[i] : *(const bfx8*)(ag[i] + s * 512);
        #pragma unroll
        for (int j = 0; j < 4; ++j) fw[j] = *(const bfx8*)(wl + j * 6144 + s * 512);
        #pragma unroll
        for (int i = 0; i < 4; ++i)
            #pragma unroll
            for (int j = 0; j < 4; ++j)
                acc[i * 4 + j] = __builtin_amdgcn_mfma_f32_16x16x32_bf16(
                    fx[i], fw[j], acc[i * 4 + j], 0, 0, 0);
    }

    #pragma unroll
    for (int j = 0; j < 4; ++j) {
        int o = o0 + j * 16 + l15;
        float bi = bias[o];
        #pragma unroll
        for (int i = 0; i < 4; ++i) {
            int npb = n0 + wave * 64 + i * 16 + quad * 4;
            f32x4 a = acc[i * 4 + j];
            float4 v = { a[0] + bi, a[1] + bi, a[2] + bi, a[3] + bi };
            *(float4*)&out[((size_t)b * Ck + o) * Nk + npb] = v;
        }
    }
}

extern "C" void kernel_launch(void* const* d_in, const int* in_sizes, int n_in,
                              void* d_out, int out_size, void* d_ws, size_t ws_size,
                              hipStream_t stream)
{
    const float* x      = (const float*)d_in[0];
    const float* w_qkv  = (const float*)d_in[1];
    const float* b_qkv  = (const float*)d_in[2];
    const float* w_proj = (const float*)d_in[3];
    const float* b_proj = (const float*)d_in[4];
    float* out = (float*)d_out;

    const size_t XT_SEG = (size_t)Bk * Nk * Ck;
    const size_t WQ_SEG = (size_t)O3 * Ck;
    const size_t WP_SEG = (size_t)Ck * Ck;
    const size_t QK_SEG = (size_t)Bk * NHk * Nk * Dp;
    const size_t V_SEG  = (size_t)Bk * NHk * Dk * Nk;

    bf16* Xs = (bf16*)d_ws;
    bf16* Wq = Xs + XT_SEG;
    bf16* Wp = Wq + WQ_SEG;
    bf16* Qs = Wp + WP_SEG;
    bf16* Ks = Qs + QK_SEG;
    bf16* Vs = Ks + QK_SEG;
    bf16* AO = Vs + V_SEG;

    prep_kernel<<<2848, 256, 0, stream>>>(x, Xs, w_qkv, w_proj, Wq, Wp, Qs, Ks);
    qkv_mfma_kernel<<<dim3(Bk, 18, 4), 256, 0, stream>>>(
        Xs, Wq, b_qkv, Qs, Ks, Vs);
    attn_kernel<<<dim3(NHk, Bk, 8), 256, 0, stream>>>(Qs, Ks, Vs, AO);
    proj_mfma_kernel<<<dim3(Bk, 6, 4), 256, 0, stream>>>(
        AO, Wp, b_proj, out);
}

// Round 8
// 122.705 us; speedup vs baseline: 3.1979x; 1.0116x over previous
//
#include <hip/hip_runtime.h>
#include <hip/hip_bf16.h>

typedef __hip_bfloat16 bf16;
typedef __bf16 bfx8 __attribute__((ext_vector_type(8)));
typedef float f32x4 __attribute__((ext_vector_type(4)));

#define Bk   8
#define Ck   384
#define NHk  8
#define Dk   48
#define Dp   64
#define Nk   1024
#define O3   1152

// ---------------------------------------------------------------------------
// R17: align XCD pinning across the producer->consumer chain.
//   qkv grid (b,by,bx): id%8==b -> batch b's Q/K/V written via XCD b's L2.
//   attn grid (b,hd,bx): id%8==b -> SAME XCD reads them (local dirty hits,
//     ~150-250cy, instead of cross-die L3 trips ~400-900cy). R13..R16 had
//     attn pinned by hd while qkv pinned by bx/b -> every staging load was
//     remote. Per-XCD attn set = batch K+V = 1.75MB < 4MB L2.
//   proj grid (b,by,bx): id%8==b -> reads attn-written AO locally.
// attn body = R13's verified 2-buffer vmcnt(0) structure (R16's 3-buffer
// counted-vmcnt + setprio was part of a measured -4us regression; dropped).
// R15 fused-run counters: phases ~80-95us real kernel time, barriers 80us
// each -> fusion dead; gaps are small; optimize kernels, not boundaries.
// ---------------------------------------------------------------------------

__device__ __forceinline__ void gload_lds16(const bf16* src, void* dst)
{
    __builtin_amdgcn_global_load_lds(
        (const __attribute__((address_space(1))) void*)src,
        (__attribute__((address_space(3))) void*)dst, 16, 0, 0);
}

__device__ __forceinline__ int pack2(float a, float b)
{
    bf16 ha = __float2bfloat16(a), hb = __float2bfloat16(b);
    unsigned lo = *(unsigned short*)&ha, hi = *(unsigned short*)&hb;
    return (int)(lo | (hi << 16));
}

__device__ __forceinline__ ushort4 pack4(float v0, float v1, float v2, float v3)
{
    bf16 h0 = __float2bfloat16(v0), h1 = __float2bfloat16(v1);
    bf16 h2 = __float2bfloat16(v2), h3 = __float2bfloat16(v3);
    ushort4 pk;
    pk.x = *(unsigned short*)&h0; pk.y = *(unsigned short*)&h1;
    pk.z = *(unsigned short*)&h2; pk.w = *(unsigned short*)&h3;
    return pk;
}

// ---------------------------------------------------------------------------
// Prep: one unit per thread (verbatim R13, verified).
// ---------------------------------------------------------------------------
__global__ __launch_bounds__(256) void prep_kernel(
    const float* __restrict__ x, bf16* __restrict__ Xs,
    const float* __restrict__ wq, const float* __restrict__ wp,
    bf16* __restrict__ Wq, bf16* __restrict__ Wp,
    bf16* __restrict__ Qs, bf16* __restrict__ Ks)
{
    const int u = blockIdx.x * 256 + threadIdx.x;
    if (u < 393216) {
        int n = u & 1023, rest = u >> 10;
        int oct = rest % 48, b = rest / 48;
        const float* xb = x + (size_t)b * Ck * Nk;
        float f[8];
        #pragma unroll
        for (int e = 0; e < 8; ++e) f[e] = xb[(size_t)(oct * 8 + e) * Nk + n];
        int4 v = { pack2(f[0], f[1]), pack2(f[2], f[3]),
                   pack2(f[4], f[5]), pack2(f[6], f[7]) };
        bf16* dst = Xs + ((size_t)b * 64 + (n >> 4)) * 6144 + oct * 128 + (n & 15) * 8;
        *(int4*)dst = v;
    } else if (u < 448512) {
        int u1 = u - 393216;
        int o = u1 % 1152, oct = u1 / 1152;
        const float* src = wq + (size_t)o * Ck + oct * 8;
        int4 v = { pack2(src[0], src[1]), pack2(src[2], src[3]),
                   pack2(src[4], src[5]), pack2(src[6], src[7]) };
        bf16* dst = Wq + ((size_t)(o >> 4) * 48 + oct) * 128 + (o & 15) * 8;
        *(int4*)dst = v;
    } else if (u < 466944) {
        int u2 = u - 448512;
        int o = u2 % 384, oct = u2 / 384;
        const float* src = wp + (size_t)o * Ck + oct * 8;
        int4 v = { pack2(src[0], src[1]), pack2(src[2], src[3]),
                   pack2(src[4], src[5]), pack2(src[6], src[7]) };
        bf16* dst = Wp + ((size_t)(o >> 4) * 48 + oct) * 128 + (o & 15) * 8;
        *(int4*)dst = v;
    } else {
        int i = u - 466944;      // 2 bufs x 64 heads x 64 grp x 2 chunks x 16
        int buf = i >> 17;
        int r17 = i & 131071;
        int head = r17 >> 11;
        int r11 = r17 & 2047;
        int g = r11 >> 5, c5 = r11 & 31;
        int cd = 6 + (c5 >> 4), e = c5 & 15;
        bf16* p = (buf ? Ks : Qs) + (size_t)head * 65536 +
                  ((size_t)g * 8 + cd) * 128 + e * 8;
        *(int4*)p = (int4){0, 0, 0, 0};
    }
}

// ---------------------------------------------------------------------------
// Kernel 1: QKV GEMM, n0=256 (verified R16). Grid (b=8, by=18, bx=4):
// id%8==b -> batch b's X/W reads and Q/K/V writes stay on XCD b.
// ---------------------------------------------------------------------------
__global__ __launch_bounds__(256, 2) void qkv_mfma_kernel(
    const bf16* __restrict__ Xs, const bf16* __restrict__ Wq,
    const float* __restrict__ bias,
    bf16* __restrict__ Qs, bf16* __restrict__ Ks, bf16* __restrict__ Vs)
{
    __shared__ __align__(16) bf16 Wl[24576];    // 48 KB

    const int b    = blockIdx.x;
    const int by   = blockIdx.y;
    const int bx   = blockIdx.z;
    const int o0   = by * 64;
    const int n0   = bx * 256;
    const int wave = threadIdx.x >> 6;
    const int lane = threadIdx.x & 63;
    const int l15  = lane & 15, quad = lane >> 4;
    const int t3   = o0 / Ck;

    {
        const bf16* wsrc = Wq + (size_t)by * 24576;
        #pragma unroll
        for (int i = 0; i < 12; ++i) {
            int f = wave * 12 + i;
            gload_lds16(wsrc + f * 512 + lane * 8, (char*)Wl + f * 1024);
        }
    }

    const bf16* xg[4];
    #pragma unroll
    for (int i = 0; i < 4; ++i)
        xg[i] = Xs + ((size_t)(b * 64 + bx * 16 + wave * 4 + i) * 48) * 128 + lane * 8;
    const bf16* wl = Wl + lane * 8;

    bfx8 fx0[4];
    #pragma unroll
    for (int i = 0; i < 4; ++i) fx0[i] = *(const bfx8*)(xg[i]);

    f32x4 acc[16];
    #pragma unroll
    for (int i = 0; i < 16; ++i) acc[i] = (f32x4){0.f, 0.f, 0.f, 0.f};

    asm volatile("s_waitcnt vmcnt(0)" ::: "memory");
    __syncthreads();

    if (t3 < 2) {
        // D: row = o (quad*4+reg), col = n (l15) -> 8B ushort4 stores
        #pragma unroll
        for (int s = 0; s < 12; ++s) {
            bfx8 fx[4], fw[4];
            #pragma unroll
            for (int i = 0; i < 4; ++i)
                fx[i] = (s == 0) ? fx0[i] : *(const bfx8*)(xg[i] + s * 512);
            #pragma unroll
            for (int j = 0; j < 4; ++j) fw[j] = *(const bfx8*)(wl + j * 6144 + s * 512);
            #pragma unroll
            for (int j = 0; j < 4; ++j)
                #pragma unroll
                for (int i = 0; i < 4; ++i)
                    acc[j * 4 + i] = __builtin_amdgcn_mfma_f32_16x16x32_bf16(
                        fw[j], fx[i], acc[j * 4 + i], 0, 0, 0);
        }
        const float qscale = 0.2082350964f;   // 48^-0.5 * log2(e)
        #pragma unroll
        for (int j = 0; j < 4; ++j) {
            int ob = o0 + j * 16 + quad * 4;
            float4 bi = *(const float4*)&bias[ob];
            int r  = ob - t3 * Ck;
            int hd = r / Dk, d0 = r - hd * Dk;
            bf16* hb = (t3 == 0 ? Qs : Ks) + (size_t)(b * NHk + hd) * 65536
                     + (d0 >> 3) * 128 + (d0 & 7);
            #pragma unroll
            for (int i = 0; i < 4; ++i) {
                int npos = n0 + wave * 64 + i * 16 + l15;
                f32x4 a = acc[j * 4 + i];
                float v0 = a[0] + bi.x, v1 = a[1] + bi.y;
                float v2 = a[2] + bi.z, v3 = a[3] + bi.w;
                if (t3 == 0) { v0 *= qscale; v1 *= qscale; v2 *= qscale; v3 *= qscale; }
                *(ushort4*)(hb + (size_t)(npos >> 4) * 1024 + (npos & 15) * 8) =
                    pack4(v0, v1, v2, v3);
            }
        }
    } else {
        // D: row = n (quad*4+reg), col = o (l15) -> 8B ushort4 stores
        #pragma unroll
        for (int s = 0; s < 12; ++s) {
            bfx8 fx[4], fw[4];
            #pragma unroll
            for (int i = 0; i < 4; ++i)
                fx[i] = (s == 0) ? fx0[i] : *(const bfx8*)(xg[i] + s * 512);
            #pragma unroll
            for (int j = 0; j < 4; ++j) fw[j] = *(const bfx8*)(wl + j * 6144 + s * 512);
            #pragma unroll
            for (int i = 0; i < 4; ++i)
                #pragma unroll
                for (int j = 0; j < 4; ++j)
                    acc[i * 4 + j] = __builtin_amdgcn_mfma_f32_16x16x32_bf16(
                        fx[i], fw[j], acc[i * 4 + j], 0, 0, 0);
        }
        #pragma unroll
        for (int j = 0; j < 4; ++j) {
            int ov = o0 + j * 16 + l15;
            float bi = bias[ov];
            int r  = ov - 2 * Ck;
            int hd = r / Dk, d = r - hd * Dk;
            bf16* vbp = Vs + (size_t)(b * NHk + hd) * 49152
                      + (size_t)(d >> 4) * 16384 + (d & 15) * 8;
            #pragma unroll
            for (int i = 0; i < 4; ++i) {
                int npb = n0 + wave * 64 + i * 16 + quad * 4;
                f32x4 a = acc[i * 4 + j];
                *(ushort4*)(vbp + (size_t)(npb >> 3) * 128 + (npb & 7)) =
                    pack4(a[0] + bi, a[1] + bi, a[2] + bi, a[3] + bi);
            }
        }
    }
}

// ---------------------------------------------------------------------------
// Kernel 2: attention — R13's verified 2-buffer body; grid re-pinned to
// (b, hd, bx) so id%8==b matches the qkv writer's XCD (local L2 dirty hits).
// ---------------------------------------------------------------------------
__global__ __launch_bounds__(256, 2) void attn_kernel(
    const bf16* __restrict__ Qs, const bf16* __restrict__ Ks,
    const bf16* __restrict__ Vs, bf16* __restrict__ AO)
{
    __shared__ __align__(16) bf16 KbL[2][4096];   // 8 KB per buf
    __shared__ __align__(16) bf16 VbL[2][3072];   // 6 KB per buf
    __shared__ __align__(16) short Ps[4 * 2 * 1152];
    __shared__ float sums[4][2][16];

    const int b    = blockIdx.x;       // id%8 == b -> XCD pin matches qkv
    const int hd   = blockIdx.y;
    const int bx   = blockIdx.z;       // 8 q-slabs of 128
    const int t    = threadIdx.x;
    const int wave = t >> 6;
    const int lane = t & 63;
    const int l15  = lane & 15;
    const int quad = lane >> 4;
    const int grp16 = (bx * 4 + wave) * 2;   // first 16-q group of this wave

    const bf16* qb = Qs + (size_t)(b * NHk + hd) * 65536;
    const bf16* kb = Ks + (size_t)(b * NHk + hd) * 65536;
    const bf16* vb = Vs + (size_t)(b * NHk + hd) * 49152;

    auto stage = [&](int buf, int k0) {
        const bf16* ksrc = kb + (size_t)k0 * 64;
        const bf16* vsrc = vb + (size_t)(k0 >> 3) * 128;
        char* kdst = (char*)&KbL[buf][0];
        char* vdst = (char*)&VbL[buf][0];
        #pragma unroll
        for (int i = 0; i < 4; ++i) {
            const int l = wave + i * 4;
            if (l < 14) {
                const int piece = l >> 1, half = l & 1;
                const bf16* src; char* dst;
                if (piece < 4) {
                    src = ksrc + piece * 1024 + half * 512 + lane * 8;
                    dst = kdst + piece * 2048 + half * 1024;
                } else {
                    const int dc = piece - 4;
                    src = vsrc + (size_t)dc * 16384 + half * 512 + lane * 8;
                    dst = vdst + dc * 2048 + half * 1024;
                }
                gload_lds16(src, dst);
            }
        }
    };

    stage(0, 0);

    bfx8 bq[2][2];
    #pragma unroll
    for (int qt = 0; qt < 2; ++qt) {
        const bf16* qp = qb + ((size_t)(grp16 + qt) * 8 + quad) * 128 + l15 * 8;
        bq[qt][0] = *(const bfx8*)(qp);
        bq[qt][1] = *(const bfx8*)(qp + 512);
    }

    float l_run[2] = {0.f, 0.f};
    f32x4 oacc[2][3];
    #pragma unroll
    for (int qt = 0; qt < 2; ++qt)
        #pragma unroll
        for (int dc = 0; dc < 3; ++dc) oacc[qt][dc] = (f32x4){0.f, 0.f, 0.f, 0.f};

    short* const PsW[2] = { Ps + wave * 2304, Ps + wave * 2304 + 1152 };
    const int lo = quad * 128 + l15 * 8;     // elem offset inside a 2KB piece

    asm volatile("s_waitcnt vmcnt(0)" ::: "memory");
    __syncthreads();

    auto step = [&](int buf, int k0, bool pf) {
        if (pf) stage(buf ^ 1, k0 + 64);     // hides under this chunk's compute

        const bf16* Kc = &KbL[buf][0];
        const bf16* Vc = &VbL[buf][0];

        f32x4 sf[2][4];
        #pragma unroll
        for (int s = 0; s < 4; ++s) {
            const bfx8 kf0 = *(const bfx8*)(Kc + s * 1024 + lo);
            const bfx8 kf1 = *(const bfx8*)(Kc + s * 1024 + 512 + lo);
            #pragma unroll
            for (int qt = 0; qt < 2; ++qt) {
                f32x4 z = (f32x4){0.f, 0.f, 0.f, 0.f};
                z = __builtin_amdgcn_mfma_f32_16x16x32_bf16(kf0, bq[qt][0], z, 0, 0, 0);
                z = __builtin_amdgcn_mfma_f32_16x16x32_bf16(kf1, bq[qt][1], z, 0, 0, 0);
                sf[qt][s] = z;
            }
        }

        #pragma unroll
        for (int qt = 0; qt < 2; ++qt) {
            float lsum = 0.f;
            #pragma unroll
            for (int s = 0; s < 4; ++s) {
                float e0 = __builtin_amdgcn_exp2f(sf[qt][s][0]);
                float e1 = __builtin_amdgcn_exp2f(sf[qt][s][1]);
                float e2 = __builtin_amdgcn_exp2f(sf[qt][s][2]);
                float e3 = __builtin_amdgcn_exp2f(sf[qt][s][3]);
                lsum += (e0 + e1) + (e2 + e3);
                *(ushort4*)&PsW[qt][l15 * 72 + s * 16 + quad * 4] =
                    pack4(e0, e1, e2, e3);
            }
            l_run[qt] += lsum;
        }

        #pragma unroll
        for (int qt = 0; qt < 2; ++qt) {
            const bfx8 ap0 = *(const bfx8*)&PsW[qt][l15 * 72 + quad * 8];
            const bfx8 ap1 = *(const bfx8*)&PsW[qt][l15 * 72 + 32 + quad * 8];
            #pragma unroll
            for (int dc = 0; dc < 3; ++dc) {
                const bfx8 bv0 = *(const bfx8*)(Vc + dc * 1024 + lo);
                const bfx8 bv1 = *(const bfx8*)(Vc + dc * 1024 + 512 + lo);
                oacc[qt][dc] = __builtin_amdgcn_mfma_f32_16x16x32_bf16(
                    ap0, bv0, oacc[qt][dc], 0, 0, 0);
                oacc[qt][dc] = __builtin_amdgcn_mfma_f32_16x16x32_bf16(
                    ap1, bv1, oacc[qt][dc], 0, 0, 0);
            }
        }

        asm volatile("s_waitcnt vmcnt(0)" ::: "memory");  // staged loads landed
        __syncthreads();                                  // buf^1 ready, buf free
    };

    #pragma unroll 1
    for (int k0 = 0; k0 < Nk; k0 += 128) {
        step(0, k0, true);
        step(1, k0 + 64, k0 + 128 < Nk);
    }

    #pragma unroll
    for (int qt = 0; qt < 2; ++qt) {
        float lt = l_run[qt];
        lt += __shfl_xor(lt, 16, 64);
        lt += __shfl_xor(lt, 32, 64);
        sums[wave][qt][l15] = lt;
    }
    asm volatile("s_waitcnt lgkmcnt(0)" ::: "memory");

    #pragma unroll
    for (int qt = 0; qt < 2; ++qt) {
        short* OsW = PsW[qt];   // 16*64 = 1024 shorts < 1152 region
        #pragma unroll
        for (int r = 0; r < 4; ++r) {
            int qi = quad * 4 + r;
            float rli = 1.0f / sums[wave][qt][qi];
            #pragma unroll
            for (int dcc = 0; dcc < 3; ++dcc) {
                bf16 hb = __float2bfloat16(oacc[qt][dcc][r] * rli);
                OsW[qi * 64 + dcc * 16 + l15] = *(short*)&hb;
            }
        }
    }
    asm volatile("s_waitcnt lgkmcnt(0)" ::: "memory");

    #pragma unroll
    for (int qt = 0; qt < 2; ++qt) {
        bf16* aob = AO + (((size_t)b * 64 + grp16 + qt) * 48 + hd * 6) * 128;
        short* OsW = PsW[qt];
        int u = lane;
        int4 v = *(const int4*)&OsW[(u & 15) * 64 + (u >> 4) * 8];
        *(int4*)(aob + u * 8) = v;
        if (lane < 32) {
            int u2 = 64 + lane;
            int4 v2 = *(const int4*)&OsW[(u2 & 15) * 64 + (u2 >> 4) * 8];
            *(int4*)(aob + u2 * 8) = v2;
        }
    }
}

// ---------------------------------------------------------------------------
// Kernel 3: projection GEMM, n0=256 (verified R16). Grid (b=8, by=6, bx=4):
// id%8==b -> reads attn-written AO from the same XCD's L2.
// ---------------------------------------------------------------------------
__global__ __launch_bounds__(256, 2) void proj_mfma_kernel(
    const bf16* __restrict__ AO, const bf16* __restrict__ Wp,
    const float* __restrict__ bias, float* __restrict__ out)
{
    __shared__ __align__(16) bf16 Wl[24576];    // 48 KB

    const int b    = blockIdx.x;
    const int by   = blockIdx.y;
    const int bx   = blockIdx.z;
    const int o0   = by * 64;
    const int n0   = bx * 256;
    const int wave = threadIdx.x >> 6;
    const int lane = threadIdx.x & 63;
    const int l15  = lane & 15, quad = lane >> 4;

    {
        const bf16* wsrc = Wp + (size_t)by * 24576;
        #pragma unroll
        for (int i = 0; i < 12; ++i) {
            int f = wave * 12 + i;
            gload_lds16(wsrc + f * 512 + lane * 8, (char*)Wl + f * 1024);
        }
    }

    const bf16* ag[4];
    #pragma unroll
    for (int i = 0; i < 4; ++i)
        ag[i] = AO + ((size_t)(b * 64 + bx * 16 + wave * 4 + i) * 48) * 128 + lane * 8;
    const bf16* wl = Wl + lane * 8;

    bfx8 fx0[4];
    #pragma unroll
    for (int i = 0; i < 4; ++i) fx0[i] = *(const bfx8*)(ag[i]);

    f32x4 acc[16];
    #pragma unroll
    for (int i = 0; i < 16; ++i) acc[i] = (f32x4){0.f, 0.f, 0.f, 0.f};

    asm volatile("s_waitcnt vmcnt(0)" ::: "memory");
    __syncthreads();

    // D: row = n (quad*4+reg), col = o (l15) -> float4 stores
    #pragma unroll
    for (int s = 0; s < 12; ++s) {
        bfx8 fx[4], fw[4];
        #pragma unroll
        for (int i = 0; i < 4; ++i)
            fx[i] = (s == 0) ? fx0[i] : *(const bfx8*)(ag[i] + s * 512);
        #pragma unroll
        for (int j = 0; j < 4; ++j) fw[j] = *(const bfx8*)(wl + j * 6144 + s * 512);
        #pragma unroll
        for (int i = 0; i < 4; ++i)
            #pragma unroll
            for (int j = 0; j < 4; ++j)
                acc[i * 4 + j] = __builtin_amdgcn_mfma_f32_16x16x32_bf16(
                    fx[i], fw[j], acc[i * 4 + j], 0, 0, 0);
    }

    #pragma unroll
    for (int j = 0; j < 4; ++j) {
        int o = o0 + j * 16 + l15;
        float bi = bias[o];
        #pragma unroll
        for (int i = 0; i < 4; ++i) {
            int npb = n0 + wave * 64 + i * 16 + quad * 4;
            f32x4 a = acc[i * 4 + j];
            float4 v = { a[0] + bi, a[1] + bi, a[2] + bi, a[3] + bi };
            *(float4*)&out[((size_t)b * Ck + o) * Nk + npb] = v;
        }
    }
}

extern "C" void kernel_launch(void* const* d_in, const int* in_sizes, int n_in,
                              void* d_out, int out_size, void* d_ws, size_t ws_size,
                              hipStream_t stream)
{
    const float* x      = (const float*)d_in[0];
    const float* w_qkv  = (const float*)d_in[1];
    const float* b_qkv  = (const float*)d_in[2];
    const float* w_proj = (const float*)d_in[3];
    const float* b_proj = (const float*)d_in[4];
    float* out = (float*)d_out;

    const size_t XT_SEG = (size_t)Bk * Nk * Ck;
    const size_t WQ_SEG = (size_t)O3 * Ck;
    const size_t WP_SEG = (size_t)Ck * Ck;
    const size_t QK_SEG = (size_t)Bk * NHk * Nk * Dp;
    const size_t V_SEG  = (size_t)Bk * NHk * Dk * Nk;

    bf16* Xs = (bf16*)d_ws;
    bf16* Wq = Xs + XT_SEG;
    bf16* Wp = Wq + WQ_SEG;
    bf16* Qs = Wp + WP_SEG;
    bf16* Ks = Qs + QK_SEG;
    bf16* Vs = Ks + QK_SEG;
    bf16* AO = Vs + V_SEG;

    prep_kernel<<<2848, 256, 0, stream>>>(x, Xs, w_qkv, w_proj, Wq, Wp, Qs, Ks);
    qkv_mfma_kernel<<<dim3(Bk, 18, 4), 256, 0, stream>>>(
        Xs, Wq, b_qkv, Qs, Ks, Vs);
    attn_kernel<<<dim3(Bk, NHk, 8), 256, 0, stream>>>(Qs, Ks, Vs, AO);
    proj_mfma_kernel<<<dim3(Bk, 6, 4), 256, 0, stream>>>(
        AO, Wp, b_proj, out);
}

// Round 9
// 119.621 us; speedup vs baseline: 3.2803x; 1.0258x over previous
//
#include <hip/hip_runtime.h>
#include <hip/hip_bf16.h>

typedef __hip_bfloat16 bf16;
typedef __bf16 bfx8 __attribute__((ext_vector_type(8)));
typedef float f32x4 __attribute__((ext_vector_type(4)));

#define Bk   8
#define Ck   384
#define NHk  8
#define Dk   48
#define Dp   64
#define Nk   1024
#define O3   1152

// ---------------------------------------------------------------------------
// R18 = R13 exact (best verified, 120.1us) + split W-stage wait in qkv/proj:
//   fx0 X-prefetch issued FIRST, then the 12 W pieces (wave w stages j=w in
//   s-order). wait vmcnt(9) [= fx0 x2 + first 3 W pieces] + barrier ->
//   compute s=0..2 while remaining 9 pieces land -> vmcnt(0) + barrier ->
//   s=3..11. Startup stall ~48KB -> ~6KB of L2 latency per block.
// Everything else byte-identical to R13. Structural gambles R14-R17 all
// regressed vs R13; reverted.
// ---------------------------------------------------------------------------

__device__ __forceinline__ void gload_lds16(const bf16* src, void* dst)
{
    __builtin_amdgcn_global_load_lds(
        (const __attribute__((address_space(1))) void*)src,
        (__attribute__((address_space(3))) void*)dst, 16, 0, 0);
}

__device__ __forceinline__ int pack2(float a, float b)
{
    bf16 ha = __float2bfloat16(a), hb = __float2bfloat16(b);
    unsigned lo = *(unsigned short*)&ha, hi = *(unsigned short*)&hb;
    return (int)(lo | (hi << 16));
}

__device__ __forceinline__ ushort4 pack4(float v0, float v1, float v2, float v3)
{
    bf16 h0 = __float2bfloat16(v0), h1 = __float2bfloat16(v1);
    bf16 h2 = __float2bfloat16(v2), h3 = __float2bfloat16(v3);
    ushort4 pk;
    pk.x = *(unsigned short*)&h0; pk.y = *(unsigned short*)&h1;
    pk.z = *(unsigned short*)&h2; pk.w = *(unsigned short*)&h3;
    return pk;
}

// ---------------------------------------------------------------------------
// Prep: one unit per thread (verbatim R13, verified).
// ---------------------------------------------------------------------------
__global__ __launch_bounds__(256) void prep_kernel(
    const float* __restrict__ x, bf16* __restrict__ Xs,
    const float* __restrict__ wq, const float* __restrict__ wp,
    bf16* __restrict__ Wq, bf16* __restrict__ Wp,
    bf16* __restrict__ Qs, bf16* __restrict__ Ks)
{
    const int u = blockIdx.x * 256 + threadIdx.x;
    if (u < 393216) {
        int n = u & 1023, rest = u >> 10;
        int oct = rest % 48, b = rest / 48;
        const float* xb = x + (size_t)b * Ck * Nk;
        float f[8];
        #pragma unroll
        for (int e = 0; e < 8; ++e) f[e] = xb[(size_t)(oct * 8 + e) * Nk + n];
        int4 v = { pack2(f[0], f[1]), pack2(f[2], f[3]),
                   pack2(f[4], f[5]), pack2(f[6], f[7]) };
        bf16* dst = Xs + ((size_t)b * 64 + (n >> 4)) * 6144 + oct * 128 + (n & 15) * 8;
        *(int4*)dst = v;
    } else if (u < 448512) {
        int u1 = u - 393216;
        int o = u1 % 1152, oct = u1 / 1152;
        const float* src = wq + (size_t)o * Ck + oct * 8;
        int4 v = { pack2(src[0], src[1]), pack2(src[2], src[3]),
                   pack2(src[4], src[5]), pack2(src[6], src[7]) };
        bf16* dst = Wq + ((size_t)(o >> 4) * 48 + oct) * 128 + (o & 15) * 8;
        *(int4*)dst = v;
    } else if (u < 466944) {
        int u2 = u - 448512;
        int o = u2 % 384, oct = u2 / 384;
        const float* src = wp + (size_t)o * Ck + oct * 8;
        int4 v = { pack2(src[0], src[1]), pack2(src[2], src[3]),
                   pack2(src[4], src[5]), pack2(src[6], src[7]) };
        bf16* dst = Wp + ((size_t)(o >> 4) * 48 + oct) * 128 + (o & 15) * 8;
        *(int4*)dst = v;
    } else {
        int i = u - 466944;      // 2 bufs x 64 heads x 64 grp x 2 chunks x 16
        int buf = i >> 17;
        int r17 = i & 131071;
        int head = r17 >> 11;
        int r11 = r17 & 2047;
        int g = r11 >> 5, c5 = r11 & 31;
        int cd = 6 + (c5 >> 4), e = c5 & 15;
        bf16* p = (buf ? Ks : Qs) + (size_t)head * 65536 +
                  ((size_t)g * 8 + cd) * 128 + e * 8;
        *(int4*)p = (int4){0, 0, 0, 0};
    }
}

// ---------------------------------------------------------------------------
// Kernel 1: QKV GEMM (R13 structure, n0=128) + split W-stage wait.
// ---------------------------------------------------------------------------
__global__ __launch_bounds__(256) void qkv_mfma_kernel(
    const bf16* __restrict__ Xs, const bf16* __restrict__ Wq,
    const float* __restrict__ bias,
    bf16* __restrict__ Qs, bf16* __restrict__ Ks, bf16* __restrict__ Vs)
{
    __shared__ __align__(16) bf16 Wl[24576];    // 48 KB

    const int b    = blockIdx.z;
    const int by   = blockIdx.y;
    const int bx   = blockIdx.x;
    const int o0   = by * 64;
    const int n0   = bx * 128;
    const int wave = threadIdx.x >> 6;
    const int lane = threadIdx.x & 63;
    const int l15  = lane & 15, quad = lane >> 4;
    const int t3   = o0 / Ck;

    const bf16* xg[2];
    #pragma unroll
    for (int i = 0; i < 2; ++i)
        xg[i] = Xs + ((size_t)(b * 64 + bx * 8 + wave * 2 + i) * 48) * 128 + lane * 8;

    // s=0 X prefetch issued FIRST so vmcnt(9) below = fx0 x2 + 3 W pieces
    bfx8 fx0[2];
    #pragma unroll
    for (int i = 0; i < 2; ++i) fx0[i] = *(const bfx8*)(xg[i]);

    // stage W tile: wave w stages piece j=w, s=i (s-order -> early s first)
    {
        const bf16* wsrc = Wq + (size_t)by * 24576;
        #pragma unroll
        for (int i = 0; i < 12; ++i) {
            int f = wave * 12 + i;
            gload_lds16(wsrc + f * 512 + lane * 8, (char*)Wl + f * 1024);
        }
    }
    const bf16* wl = Wl + lane * 8;

    f32x4 acc[8];
    #pragma unroll
    for (int i = 0; i < 8; ++i) acc[i] = (f32x4){0.f, 0.f, 0.f, 0.f};

    // phase A: s=0..2 W pieces resident (own 3 stages done at barrier)
    asm volatile("s_waitcnt vmcnt(9)" ::: "memory");
    __builtin_amdgcn_sched_barrier(0);
    __syncthreads();

    if (t3 < 2) {
        #pragma unroll
        for (int s = 0; s < 3; ++s) {
            bfx8 fx[2], fw[4];
            #pragma unroll
            for (int i = 0; i < 2; ++i)
                fx[i] = (s == 0) ? fx0[i] : *(const bfx8*)(xg[i] + s * 512);
            #pragma unroll
            for (int j = 0; j < 4; ++j) fw[j] = *(const bfx8*)(wl + j * 6144 + s * 512);
            #pragma unroll
            for (int j = 0; j < 4; ++j)
                #pragma unroll
                for (int i = 0; i < 2; ++i)
                    acc[j * 2 + i] = __builtin_amdgcn_mfma_f32_16x16x32_bf16(
                        fw[j], fx[i], acc[j * 2 + i], 0, 0, 0);
        }
        asm volatile("s_waitcnt vmcnt(0)" ::: "memory");
        __builtin_amdgcn_sched_barrier(0);
        __syncthreads();
        #pragma unroll
        for (int s = 3; s < 12; ++s) {
            bfx8 fx[2], fw[4];
            #pragma unroll
            for (int i = 0; i < 2; ++i) fx[i] = *(const bfx8*)(xg[i] + s * 512);
            #pragma unroll
            for (int j = 0; j < 4; ++j) fw[j] = *(const bfx8*)(wl + j * 6144 + s * 512);
            #pragma unroll
            for (int j = 0; j < 4; ++j)
                #pragma unroll
                for (int i = 0; i < 2; ++i)
                    acc[j * 2 + i] = __builtin_amdgcn_mfma_f32_16x16x32_bf16(
                        fw[j], fx[i], acc[j * 2 + i], 0, 0, 0);
        }
        const float qscale = 0.2082350964f;   // 48^-0.5 * log2(e)
        #pragma unroll
        for (int j = 0; j < 4; ++j) {
            int ob = o0 + j * 16 + quad * 4;          // o of reg 0 (mult of 4)
            float4 bi = *(const float4*)&bias[ob];
            int r  = ob - t3 * Ck;
            int hd = r / Dk, d0 = r - hd * Dk;        // d0..d0+3, same octet
            bf16* hb = (t3 == 0 ? Qs : Ks) + (size_t)(b * NHk + hd) * 65536
                     + (d0 >> 3) * 128 + (d0 & 7);
            #pragma unroll
            for (int i = 0; i < 2; ++i) {
                int npos = n0 + wave * 32 + i * 16 + l15;
                f32x4 a = acc[j * 2 + i];
                float v0 = a[0] + bi.x, v1 = a[1] + bi.y;
                float v2 = a[2] + bi.z, v3 = a[3] + bi.w;
                if (t3 == 0) { v0 *= qscale; v1 *= qscale; v2 *= qscale; v3 *= qscale; }
                *(ushort4*)(hb + (size_t)(npos >> 4) * 1024 + (npos & 15) * 8) =
                    pack4(v0, v1, v2, v3);
            }
        }
    } else {
        #pragma unroll
        for (int s = 0; s < 3; ++s) {
            bfx8 fx[2], fw[4];
            #pragma unroll
            for (int i = 0; i < 2; ++i)
                fx[i] = (s == 0) ? fx0[i] : *(const bfx8*)(xg[i] + s * 512);
            #pragma unroll
            for (int j = 0; j < 4; ++j) fw[j] = *(const bfx8*)(wl + j * 6144 + s * 512);
            #pragma unroll
            for (int i = 0; i < 2; ++i)
                #pragma unroll
                for (int j = 0; j < 4; ++j)
                    acc[i * 4 + j] = __builtin_amdgcn_mfma_f32_16x16x32_bf16(
                        fx[i], fw[j], acc[i * 4 + j], 0, 0, 0);
        }
        asm volatile("s_waitcnt vmcnt(0)" ::: "memory");
        __builtin_amdgcn_sched_barrier(0);
        __syncthreads();
        #pragma unroll
        for (int s = 3; s < 12; ++s) {
            bfx8 fx[2], fw[4];
            #pragma unroll
            for (int i = 0; i < 2; ++i) fx[i] = *(const bfx8*)(xg[i] + s * 512);
            #pragma unroll
            for (int j = 0; j < 4; ++j) fw[j] = *(const bfx8*)(wl + j * 6144 + s * 512);
            #pragma unroll
            for (int i = 0; i < 2; ++i)
                #pragma unroll
                for (int j = 0; j < 4; ++j)
                    acc[i * 4 + j] = __builtin_amdgcn_mfma_f32_16x16x32_bf16(
                        fx[i], fw[j], acc[i * 4 + j], 0, 0, 0);
        }
        #pragma unroll
        for (int j = 0; j < 4; ++j) {
            int ov = o0 + j * 16 + l15;
            float bi = bias[ov];
            int r  = ov - 2 * Ck;
            int hd = r / Dk, d = r - hd * Dk;
            bf16* vbp = Vs + (size_t)(b * NHk + hd) * 49152
                      + (size_t)(d >> 4) * 16384 + (d & 15) * 8;
            #pragma unroll
            for (int i = 0; i < 2; ++i) {
                int npb = n0 + wave * 32 + i * 16 + quad * 4;   // n of reg 0
                f32x4 a = acc[i * 4 + j];
                *(ushort4*)(vbp + (size_t)(npb >> 3) * 128 + (npb & 7)) =
                    pack4(a[0] + bi, a[1] + bi, a[2] + bi, a[3] + bi);
            }
        }
    }
}

// ---------------------------------------------------------------------------
// Kernel 2: MFMA attention, LDS-staged K/V (verbatim R13, verified).
// ---------------------------------------------------------------------------
__global__ __launch_bounds__(256, 2) void attn_kernel(
    const bf16* __restrict__ Qs, const bf16* __restrict__ Ks,
    const bf16* __restrict__ Vs, bf16* __restrict__ AO)
{
    __shared__ __align__(16) bf16 KbL[2][4096];   // 8 KB per buf
    __shared__ __align__(16) bf16 VbL[2][3072];   // 6 KB per buf
    __shared__ __align__(16) short Ps[4 * 2 * 1152];
    __shared__ float sums[4][2][16];

    const int hd   = blockIdx.x;
    const int b    = blockIdx.y;
    const int bx   = blockIdx.z;       // 8 q-slabs of 128
    const int t    = threadIdx.x;
    const int wave = t >> 6;
    const int lane = t & 63;
    const int l15  = lane & 15;
    const int quad = lane >> 4;
    const int grp16 = (bx * 4 + wave) * 2;   // first 16-q group of this wave

    const bf16* qb = Qs + (size_t)(b * NHk + hd) * 65536;
    const bf16* kb = Ks + (size_t)(b * NHk + hd) * 65536;
    const bf16* vb = Vs + (size_t)(b * NHk + hd) * 49152;

    auto stage = [&](int buf, int k0) {
        const bf16* ksrc = kb + (size_t)k0 * 64;
        const bf16* vsrc = vb + (size_t)(k0 >> 3) * 128;
        char* kdst = (char*)&KbL[buf][0];
        char* vdst = (char*)&VbL[buf][0];
        #pragma unroll
        for (int i = 0; i < 4; ++i) {
            const int l = wave + i * 4;
            if (l < 14) {
                const int piece = l >> 1, half = l & 1;
                const bf16* src; char* dst;
                if (piece < 4) {
                    src = ksrc + piece * 1024 + half * 512 + lane * 8;
                    dst = kdst + piece * 2048 + half * 1024;
                } else {
                    const int dc = piece - 4;
                    src = vsrc + (size_t)dc * 16384 + half * 512 + lane * 8;
                    dst = vdst + dc * 2048 + half * 1024;
                }
                gload_lds16(src, dst);
            }
        }
    };

    stage(0, 0);

    bfx8 bq[2][2];
    #pragma unroll
    for (int qt = 0; qt < 2; ++qt) {
        const bf16* qp = qb + ((size_t)(grp16 + qt) * 8 + quad) * 128 + l15 * 8;
        bq[qt][0] = *(const bfx8*)(qp);
        bq[qt][1] = *(const bfx8*)(qp + 512);
    }

    float l_run[2] = {0.f, 0.f};
    f32x4 oacc[2][3];
    #pragma unroll
    for (int qt = 0; qt < 2; ++qt)
        #pragma unroll
        for (int dc = 0; dc < 3; ++dc) oacc[qt][dc] = (f32x4){0.f, 0.f, 0.f, 0.f};

    short* const PsW[2] = { Ps + wave * 2304, Ps + wave * 2304 + 1152 };
    const int lo = quad * 128 + l15 * 8;     // elem offset inside a 2KB piece

    asm volatile("s_waitcnt vmcnt(0)" ::: "memory");
    __syncthreads();

    auto step = [&](int buf, int k0, bool pf) {
        if (pf) stage(buf ^ 1, k0 + 64);     // hides under this chunk's compute

        const bf16* Kc = &KbL[buf][0];
        const bf16* Vc = &VbL[buf][0];

        f32x4 sf[2][4];
        #pragma unroll
        for (int s = 0; s < 4; ++s) {
            const bfx8 kf0 = *(const bfx8*)(Kc + s * 1024 + lo);
            const bfx8 kf1 = *(const bfx8*)(Kc + s * 1024 + 512 + lo);
            #pragma unroll
            for (int qt = 0; qt < 2; ++qt) {
                f32x4 z = (f32x4){0.f, 0.f, 0.f, 0.f};
                z = __builtin_amdgcn_mfma_f32_16x16x32_bf16(kf0, bq[qt][0], z, 0, 0, 0);
                z = __builtin_amdgcn_mfma_f32_16x16x32_bf16(kf1, bq[qt][1], z, 0, 0, 0);
                sf[qt][s] = z;
            }
        }

        #pragma unroll
        for (int qt = 0; qt < 2; ++qt) {
            float lsum = 0.f;
            #pragma unroll
            for (int s = 0; s < 4; ++s) {
                float e0 = __builtin_amdgcn_exp2f(sf[qt][s][0]);
                float e1 = __builtin_amdgcn_exp2f(sf[qt][s][1]);
                float e2 = __builtin_amdgcn_exp2f(sf[qt][s][2]);
                float e3 = __builtin_amdgcn_exp2f(sf[qt][s][3]);
                lsum += (e0 + e1) + (e2 + e3);
                *(ushort4*)&PsW[qt][l15 * 72 + s * 16 + quad * 4] =
                    pack4(e0, e1, e2, e3);
            }
            l_run[qt] += lsum;
        }

        #pragma unroll
        for (int qt = 0; qt < 2; ++qt) {
            const bfx8 ap0 = *(const bfx8*)&PsW[qt][l15 * 72 + quad * 8];
            const bfx8 ap1 = *(const bfx8*)&PsW[qt][l15 * 72 + 32 + quad * 8];
            #pragma unroll
            for (int dc = 0; dc < 3; ++dc) {
                const bfx8 bv0 = *(const bfx8*)(Vc + dc * 1024 + lo);
                const bfx8 bv1 = *(const bfx8*)(Vc + dc * 1024 + 512 + lo);
                oacc[qt][dc] = __builtin_amdgcn_mfma_f32_16x16x32_bf16(
                    ap0, bv0, oacc[qt][dc], 0, 0, 0);
                oacc[qt][dc] = __builtin_amdgcn_mfma_f32_16x16x32_bf16(
                    ap1, bv1, oacc[qt][dc], 0, 0, 0);
            }
        }

        asm volatile("s_waitcnt vmcnt(0)" ::: "memory");  // staged loads landed
        __syncthreads();                                  // buf^1 ready, buf free
    };

    #pragma unroll 1
    for (int k0 = 0; k0 < Nk; k0 += 128) {
        step(0, k0, true);
        step(1, k0 + 64, k0 + 128 < Nk);
    }

    #pragma unroll
    for (int qt = 0; qt < 2; ++qt) {
        float lt = l_run[qt];
        lt += __shfl_xor(lt, 16, 64);
        lt += __shfl_xor(lt, 32, 64);
        sums[wave][qt][l15] = lt;
    }
    asm volatile("s_waitcnt lgkmcnt(0)" ::: "memory");

    #pragma unroll
    for (int qt = 0; qt < 2; ++qt) {
        short* OsW = PsW[qt];   // 16*64 = 1024 shorts < 1152 region
        #pragma unroll
        for (int r = 0; r < 4; ++r) {
            int qi = quad * 4 + r;
            float rli = 1.0f / sums[wave][qt][qi];
            #pragma unroll
            for (int dcc = 0; dcc < 3; ++dcc) {
                bf16 hb = __float2bfloat16(oacc[qt][dcc][r] * rli);
                OsW[qi * 64 + dcc * 16 + l15] = *(short*)&hb;
            }
        }
    }
    asm volatile("s_waitcnt lgkmcnt(0)" ::: "memory");

    #pragma unroll
    for (int qt = 0; qt < 2; ++qt) {
        bf16* aob = AO + (((size_t)b * 64 + grp16 + qt) * 48 + hd * 6) * 128;
        short* OsW = PsW[qt];
        int u = lane;
        int4 v = *(const int4*)&OsW[(u & 15) * 64 + (u >> 4) * 8];
        *(int4*)(aob + u * 8) = v;
        if (lane < 32) {
            int u2 = 64 + lane;
            int4 v2 = *(const int4*)&OsW[(u2 & 15) * 64 + (u2 >> 4) * 8];
            *(int4*)(aob + u2 * 8) = v2;
        }
    }
}

// ---------------------------------------------------------------------------
// Kernel 3: projection GEMM (R13 structure, n0=128) + split W-stage wait.
// ---------------------------------------------------------------------------
__global__ __launch_bounds__(256) void proj_mfma_kernel(
    const bf16* __restrict__ AO, const bf16* __restrict__ Wp,
    const float* __restrict__ bias, float* __restrict__ out)
{
    __shared__ __align__(16) bf16 Wl[24576];    // 48 KB

    const int b    = blockIdx.z;
    const int by   = blockIdx.y;
    const int bx   = blockIdx.x;
    const int o0   = by * 64;
    const int n0   = bx * 128;
    const int wave = threadIdx.x >> 6;
    const int lane = threadIdx.x & 63;
    const int l15  = lane & 15, quad = lane >> 4;

    const bf16* ag[2];
    #pragma unroll
    for (int i = 0; i < 2; ++i)
        ag[i] = AO + ((size_t)(b * 64 + bx * 8 + wave * 2 + i) * 48) * 128 + lane * 8;

    bfx8 fx0[2];
    #pragma unroll
    for (int i = 0; i < 2; ++i) fx0[i] = *(const bfx8*)(ag[i]);

    {
        const bf16* wsrc = Wp + (size_t)by * 24576;
        #pragma unroll
        for (int i = 0; i < 12; ++i) {
            int f = wave * 12 + i;
            gload_lds16(wsrc + f * 512 + lane * 8, (char*)Wl + f * 1024);
        }
    }
    const bf16* wl = Wl + lane * 8;

    f32x4 acc[8];
    #pragma unroll
    for (int i = 0; i < 8; ++i) acc[i] = (f32x4){0.f, 0.f, 0.f, 0.f};

    asm volatile("s_waitcnt vmcnt(9)" ::: "memory");
    __builtin_amdgcn_sched_barrier(0);
    __syncthreads();

    // D: row = n (quad*4+reg), col = o (l15) -> float4 stores
    #pragma unroll
    for (int s = 0; s < 3; ++s) {
        bfx8 fx[2], fw[4];
        #pragma unroll
        for (int i = 0; i < 2; ++i)
            fx[i] = (s == 0) ? fx0[i] : *(const bfx8*)(ag[i] + s * 512);
        #pragma unroll
        for (int j = 0; j < 4; ++j) fw[j] = *(const bfx8*)(wl + j * 6144 + s * 512);
        #pragma unroll
        for (int i = 0; i < 2; ++i)
            #pragma unroll
            for (int j = 0; j < 4; ++j)
                acc[i * 4 + j] = __builtin_amdgcn_mfma_f32_16x16x32_bf16(
                    fx[i], fw[j], acc[i * 4 + j], 0, 0, 0);
    }
    asm volatile("s_waitcnt vmcnt(0)" ::: "memory");
    __builtin_amdgcn_sched_barrier(0);
    __syncthreads();
    #pragma unroll
    for (int s = 3; s < 12; ++s) {
        bfx8 fx[2], fw[4];
        #pragma unroll
        for (int i = 0; i < 2; ++i) fx[i] = *(const bfx8*)(ag[i] + s * 512);
        #pragma unroll
        for (int j = 0; j < 4; ++j) fw[j] = *(const bfx8*)(wl + j * 6144 + s * 512);
        #pragma unroll
        for (int i = 0; i < 2; ++i)
            #pragma unroll
            for (int j = 0; j < 4; ++j)
                acc[i * 4 + j] = __builtin_amdgcn_mfma_f32_16x16x32_bf16(
                    fx[i], fw[j], acc[i * 4 + j], 0, 0, 0);
    }

    #pragma unroll
    for (int j = 0; j < 4; ++j) {
        int o = o0 + j * 16 + l15;
        float bi = bias[o];
        #pragma unroll
        for (int i = 0; i < 2; ++i) {
            int npb = n0 + wave * 32 + i * 16 + quad * 4;
            f32x4 a = acc[i * 4 + j];
            float4 v = { a[0] + bi, a[1] + bi, a[2] + bi, a[3] + bi };
            *(float4*)&out[((size_t)b * Ck + o) * Nk + npb] = v;
        }
    }
}

extern "C" void kernel_launch(void* const* d_in, const int* in_sizes, int n_in,
                              void* d_out, int out_size, void* d_ws, size_t ws_size,
                              hipStream_t stream)
{
    const float* x      = (const float*)d_in[0];
    const float* w_qkv  = (const float*)d_in[1];
    const float* b_qkv  = (const float*)d_in[2];
    const float* w_proj = (const float*)d_in[3];
    const float* b_proj = (const float*)d_in[4];
    float* out = (float*)d_out;

    const size_t XT_SEG = (size_t)Bk * Nk * Ck;
    const size_t WQ_SEG = (size_t)O3 * Ck;
    const size_t WP_SEG = (size_t)Ck * Ck;
    const size_t QK_SEG = (size_t)Bk * NHk * Nk * Dp;
    const size_t V_SEG  = (size_t)Bk * NHk * Dk * Nk;

    bf16* Xs = (bf16*)d_ws;
    bf16* Wq = Xs + XT_SEG;
    bf16* Wp = Wq + WQ_SEG;
    bf16* Qs = Wp + WP_SEG;
    bf16* Ks = Qs + QK_SEG;
    bf16* Vs = Ks + QK_SEG;
    bf16* AO = Vs + V_SEG;

    prep_kernel<<<2848, 256, 0, stream>>>(x, Xs, w_qkv, w_proj, Wq, Wp, Qs, Ks);
    qkv_mfma_kernel<<<dim3(Nk / 128, O3 / 64, Bk), 256, 0, stream>>>(
        Xs, Wq, b_qkv, Qs, Ks, Vs);
    attn_kernel<<<dim3(NHk, Bk, 8), 256, 0, stream>>>(Qs, Ks, Vs, AO);
    proj_mfma_kernel<<<dim3(Nk / 128, Ck / 64, Bk), 256, 0, stream>>>(
        AO, Wp, b_proj, out);
}